// Round 10
// baseline (791.061 us; speedup 1.0000x reference)
//
#include <hip/hip_runtime.h>

#define N_NODES 50000
#define N_EDGES 800000
#define D 256
#define NCLS 40
#define NP 50176   // 196*256 padded histogram/scan size (>= N_NODES+1)
#define NB 196
#define BN_EPS 1e-5f

typedef __attribute__((ext_vector_type(8))) short bf16x8;
typedef __attribute__((ext_vector_type(4))) float f32x4;

__device__ __forceinline__ unsigned short f2bf(float x) {
  unsigned u = __builtin_bit_cast(unsigned, x);
  unsigned r = (u + 0x7FFFu + ((u >> 16) & 1u)) >> 16;
  return (unsigned short)r;
}
__device__ __forceinline__ float bf2f(unsigned short h) {
  unsigned u = ((unsigned)h) << 16;
  return __builtin_bit_cast(float, u);
}

// ================= CSR build =================
__global__ void k_hist(const int* __restrict__ dst, int* __restrict__ cnt) {
  int i = blockIdx.x * blockDim.x + threadIdx.x;
  int stride = gridDim.x * blockDim.x;
  for (; i < N_EDGES; i += stride) atomicAdd(&cnt[dst[i] + 1], 1);
}

__global__ void k_scan1(int* __restrict__ a, int* __restrict__ bsum) {
  __shared__ int s[256];
  int i = blockIdx.x * 256 + threadIdx.x;
  s[threadIdx.x] = a[i];
  __syncthreads();
#pragma unroll
  for (int o = 1; o < 256; o <<= 1) {
    int t = (threadIdx.x >= o) ? s[threadIdx.x - o] : 0;
    __syncthreads();
    s[threadIdx.x] += t;
    __syncthreads();
  }
  a[i] = s[threadIdx.x];
  if (threadIdx.x == 255) bsum[blockIdx.x] = s[255];
}

__global__ void k_scan2(int* __restrict__ bsum) {
  __shared__ int s[256];
  int t = threadIdx.x;
  s[t] = (t < NB) ? bsum[t] : 0;
  __syncthreads();
#pragma unroll
  for (int o = 1; o < 256; o <<= 1) {
    int x = (t >= o) ? s[t - o] : 0;
    __syncthreads();
    s[t] += x;
    __syncthreads();
  }
  if (t < NB) bsum[t] = (t == 0) ? 0 : s[t - 1];
}

__global__ void k_scan3(int* __restrict__ a, const int* __restrict__ bsum) {
  if (blockIdx.x == 0) return;
  int i = blockIdx.x * 256 + threadIdx.x;
  a[i] += bsum[blockIdx.x];
}

__global__ void k_copycur(const int* __restrict__ off, int* __restrict__ cur) {
  int i = blockIdx.x * blockDim.x + threadIdx.x;
  if (i < N_NODES) cur[i] = off[i];
}

__global__ void k_fill(const int* __restrict__ src, const int* __restrict__ dst,
                       int* __restrict__ cur, int* __restrict__ esrc) {
  int i = blockIdx.x * blockDim.x + threadIdx.x;
  int stride = gridDim.x * blockDim.x;
  for (; i < N_EDGES; i += stride) {
    int p = atomicAdd(&cur[dst[i]], 1);
    esrc[p] = src[i];
  }
}

// ====== gather-mean over bf16 table (stride-512 rows), output bf16 ======
// unroll-4: 4 independent row loads in flight to hide L2/L3/HBM latency
__global__ __launch_bounds__(256) void k_gather_bf(const unsigned short* __restrict__ feat,
                                                   const int* __restrict__ off,
                                                   const int* __restrict__ esrc,
                                                   unsigned short* __restrict__ aggout) {
  int wave = blockIdx.x * 4 + (threadIdx.x >> 6);
  int lane = threadIdx.x & 63;
  if (wave >= N_NODES) return;
  int s0 = off[wave], s1 = off[wave + 1];
  float a0 = 0.f, a1 = 0.f, a2 = 0.f, a3 = 0.f;
  int j = s0;
  for (; j + 3 < s1; j += 4) {
    int sa = esrc[j], sb = esrc[j + 1], sc = esrc[j + 2], sd = esrc[j + 3];
    ushort4 va = *(const ushort4*)&feat[(size_t)sa * 512 + lane * 4];
    ushort4 vb = *(const ushort4*)&feat[(size_t)sb * 512 + lane * 4];
    ushort4 vc = *(const ushort4*)&feat[(size_t)sc * 512 + lane * 4];
    ushort4 vd = *(const ushort4*)&feat[(size_t)sd * 512 + lane * 4];
    a0 += (bf2f(va.x) + bf2f(vb.x)) + (bf2f(vc.x) + bf2f(vd.x));
    a1 += (bf2f(va.y) + bf2f(vb.y)) + (bf2f(vc.y) + bf2f(vd.y));
    a2 += (bf2f(va.z) + bf2f(vb.z)) + (bf2f(vc.z) + bf2f(vd.z));
    a3 += (bf2f(va.w) + bf2f(vb.w)) + (bf2f(vc.w) + bf2f(vd.w));
  }
  for (; j < s1; ++j) {
    int sa = esrc[j];
    ushort4 va = *(const ushort4*)&feat[(size_t)sa * 512 + lane * 4];
    a0 += bf2f(va.x); a1 += bf2f(va.y); a2 += bf2f(va.z); a3 += bf2f(va.w);
  }
  float inv = 1.0f / fmaxf((float)(s1 - s0), 1.0f);
  ushort4 o;
  o.x = f2bf(a0 * inv); o.y = f2bf(a1 * inv);
  o.z = f2bf(a2 * inv); o.w = f2bf(a3 * inv);
  *(ushort4*)&aggout[(size_t)wave * 512 + lane * 4] = o;
}

// ====== gather-mean (40 ch, f32 P) fused with final epilogue; unroll-4 ======
__global__ __launch_bounds__(256) void k_gather40(const float* __restrict__ P,
                                                  const int* __restrict__ off,
                                                  const int* __restrict__ esrc,
                                                  const float* __restrict__ b2,
                                                  float* __restrict__ out) {
  int wave = blockIdx.x * 4 + (threadIdx.x >> 6);
  int lane = threadIdx.x & 63;
  if (wave >= N_NODES || lane >= NCLS) return;
  int s0 = off[wave], s1 = off[wave + 1];
  float acc = 0.f;
  int j = s0;
  for (; j + 3 < s1; j += 4) {
    int sa = esrc[j], sb = esrc[j + 1], sc = esrc[j + 2], sd = esrc[j + 3];
    float va = P[(size_t)sa * 80 + NCLS + lane];
    float vb = P[(size_t)sb * 80 + NCLS + lane];
    float vc = P[(size_t)sc * 80 + NCLS + lane];
    float vd = P[(size_t)sd * 80 + NCLS + lane];
    acc += (va + vb) + (vc + vd);
  }
  for (; j < s1; ++j) {
    int s = esrc[j];
    acc += P[(size_t)s * 80 + NCLS + lane];
  }
  float inv = 1.0f / fmaxf((float)(s1 - s0), 1.0f);
  out[(size_t)wave * NCLS + lane] = P[(size_t)wave * 80 + lane] + b2[lane] + acc * inv;
}

// ====== f32 -> hi/lo bf16 planes (layer-0 LLM features) ======
__global__ void k_cvt(const float* __restrict__ x, unsigned short* __restrict__ hi,
                      unsigned short* __restrict__ lo) {
  int i = blockIdx.x * blockDim.x + threadIdx.x;
  int stride = gridDim.x * blockDim.x;
  const int n4 = N_NODES * D / 4;
  for (; i < n4; i += stride) {
    int row = i >> 6;
    int c4 = (i & 63) * 4;
    float4 v = ((const float4*)x)[i];
    ushort4 h, l;
    h.x = f2bf(v.x); l.x = f2bf(v.x - bf2f(h.x));
    h.y = f2bf(v.y); l.y = f2bf(v.y - bf2f(h.y));
    h.z = f2bf(v.z); l.z = f2bf(v.z - bf2f(h.z));
    h.w = f2bf(v.w); l.w = f2bf(v.w - bf2f(h.w));
    *(ushort4*)&hi[(size_t)row * 512 + c4] = h;
    *(ushort4*)&lo[(size_t)row * 256 + c4] = l;
  }
}

// ====== weight split: Wcat [256][512] hi/lo from W1,W2 [256][256] ======
__global__ void k_wsplit512(const float* __restrict__ W1, const float* __restrict__ W2,
                            unsigned short* __restrict__ Wh, unsigned short* __restrict__ Wl) {
  int i = blockIdx.x * blockDim.x + threadIdx.x;  // 256*128 threads, 4 elems each
  if (i >= 256 * 128) return;
  int row = i >> 7;
  int c4 = (i & 127) * 4;
  const float* srcp = (c4 < 256) ? &W1[(size_t)row * 256 + c4] : &W2[(size_t)row * 256 + c4 - 256];
  float4 v = *(const float4*)srcp;
  ushort4 h, l;
  h.x = f2bf(v.x); l.x = f2bf(v.x - bf2f(h.x));
  h.y = f2bf(v.y); l.y = f2bf(v.y - bf2f(h.y));
  h.z = f2bf(v.z); l.z = f2bf(v.z - bf2f(h.z));
  h.w = f2bf(v.w); l.w = f2bf(v.w - bf2f(h.w));
  *(ushort4*)&Wh[(size_t)row * 512 + c4] = h;
  *(ushort4*)&Wl[(size_t)row * 512 + c4] = l;
}

// ====== weight split layer 2: Wcat2 [80][256] hi/lo from ws2,wn2 [40][256] ======
__global__ void k_wsplit2(const float* __restrict__ ws2, const float* __restrict__ wn2,
                          unsigned short* __restrict__ Wh, unsigned short* __restrict__ Wl) {
  int i = blockIdx.x * blockDim.x + threadIdx.x;  // 80*64 threads, 4 elems each
  if (i >= 80 * 64) return;
  int row = i >> 6;
  int c4 = (i & 63) * 4;
  const float* srcp = (row < NCLS) ? &ws2[(size_t)row * 256 + c4]
                                   : &wn2[(size_t)(row - NCLS) * 256 + c4];
  float4 v = *(const float4*)srcp;
  ushort4 h, l;
  h.x = f2bf(v.x); l.x = f2bf(v.x - bf2f(h.x));
  h.y = f2bf(v.y); l.y = f2bf(v.y - bf2f(h.y));
  h.z = f2bf(v.z); l.z = f2bf(v.z - bf2f(h.z));
  h.w = f2bf(v.w); l.w = f2bf(v.w - bf2f(h.w));
  *(ushort4*)&Wh[(size_t)row * 256 + c4] = h;
  *(ushort4*)&Wl[(size_t)row * 256 + c4] = l;
}

// ========== bf16 MFMA GEMM: A staged via LDS (pipelined), W direct from L2 ==========
// Out[M x ncol] = A @ W^T (+bias). A: hi plane (stride strideA) + lo plane (stride 256,
// only K-steps s < NLO). W: hi/lo planes read directly from global (L2-resident, 0.5 MB).
// 3 MFMA passes (ah*wh + ah*wl + al*wh) for s<NLO, 2 passes otherwise.
// 128x128 tile, BK=64, 4 waves; A-prefetch: next step's registers load during compute.
template <int NSTEPS, int NLO, bool HASBIAS>
__global__ __launch_bounds__(256) void k_bgemm(
    const unsigned short* __restrict__ Ah, int strideA,
    const unsigned short* __restrict__ Al,
    const unsigned short* __restrict__ Wh, const unsigned short* __restrict__ Wl, int strideW,
    const float* __restrict__ bias,
    float* __restrict__ Out, int M, int ncol, int ldc) {
  __shared__ short sAh[128 * 64], sAl[128 * 64];   // 32 KB total
  const int tid = threadIdx.x;
  const int lane = tid & 63;
  const int wv = tid >> 6;
  const int wr = wv >> 1, wc = wv & 1;
  const int m0 = blockIdx.x * 128, n0 = blockIdx.y * 128;

  f32x4 acc[4][4] = {};

  const int sr = tid >> 1;            // staging row 0..127
  const int sk2 = (tid & 1) * 32;     // bf16 col offset 0/32
  int arow = m0 + sr; if (arow > M - 1) arow = M - 1;

  // W fragment rows (clamped once); fragment K-offset within a 32-wide k-slot
  int wrow[4];
#pragma unroll
  for (int i = 0; i < 4; ++i) {
    int r = n0 + wc * 64 + i * 16 + (lane & 15);
    wrow[i] = (r > ncol - 1) ? (ncol - 1) : r;
  }
  const int kfrag = (lane >> 4) * 8;  // 0,8,16,24 bf16

  // prefetch step 0 A into registers
  bf16x8 cA[4], cAl[4];
  {
    const unsigned short* pa  = Ah + (size_t)arow * strideA + sk2;
    const unsigned short* pal = Al + (size_t)arow * 256 + sk2;
#pragma unroll
    for (int c = 0; c < 4; ++c) {
      cA[c] = *(const bf16x8*)(pa + c * 8);
      if (NLO > 0) cAl[c] = *(const bf16x8*)(pal + c * 8);
    }
  }

#pragma unroll
  for (int s = 0; s < NSTEPS; ++s) {
    const bool withLo = (s < NLO);
    const int k0 = s * 64;
    __syncthreads();  // previous step's LDS reads complete
#pragma unroll
    for (int c = 0; c < 4; ++c) {
      int byte = (sk2 + c * 8) * 2;
      int idx = (sr * 128 + (byte ^ ((sr & 7) << 4))) >> 1;
      *(bf16x8*)&sAh[idx] = cA[c];
      if (withLo) *(bf16x8*)&sAl[idx] = cAl[c];
    }
    // issue next step's A loads now — they complete under this step's MFMAs
    if (s + 1 < NSTEPS) {
      const int k1 = (s + 1) * 64;
      const unsigned short* pa  = Ah + (size_t)arow * strideA + k1 + sk2;
      const unsigned short* pal = Al + (size_t)arow * 256 + k1 + sk2;
#pragma unroll
      for (int c = 0; c < 4; ++c) {
        cA[c] = *(const bf16x8*)(pa + c * 8);
        if (s + 1 < NLO) cAl[c] = *(const bf16x8*)(pal + c * 8);
      }
    }
    __syncthreads();  // LDS writes visible
#pragma unroll
    for (int ks = 0; ks < 2; ++ks) {
      const int kb = ks * 64 + (lane >> 4) * 16;  // LDS byte offset in 128B row
      bf16x8 a_h[4], a_l[4], w_h[4], w_l[4];
#pragma unroll
      for (int i = 0; i < 4; ++i) {
        int rowA = wr * 64 + i * 16 + (lane & 15);
        int adA = (rowA * 128 + (kb ^ ((rowA & 7) << 4))) >> 1;
        a_h[i] = *(bf16x8*)&sAh[adA];
        if (withLo) a_l[i] = *(bf16x8*)&sAl[adA];
        const size_t woff = (size_t)wrow[i] * strideW + k0 + ks * 32 + kfrag;
        w_h[i] = *(const bf16x8*)(Wh + woff);
        w_l[i] = *(const bf16x8*)(Wl + woff);
      }
#pragma unroll
      for (int i = 0; i < 4; ++i)
#pragma unroll
        for (int j = 0; j < 4; ++j) {
          acc[i][j] = __builtin_amdgcn_mfma_f32_16x16x32_bf16(a_h[i], w_h[j], acc[i][j], 0, 0, 0);
          acc[i][j] = __builtin_amdgcn_mfma_f32_16x16x32_bf16(a_h[i], w_l[j], acc[i][j], 0, 0, 0);
          if (withLo)
            acc[i][j] = __builtin_amdgcn_mfma_f32_16x16x32_bf16(a_l[i], w_h[j], acc[i][j], 0, 0, 0);
        }
    }
  }
  // epilogue: C[row][col], col = lane&15 (+frag), row = (lane>>4)*4 + r (+frag)
#pragma unroll
  for (int j = 0; j < 4; ++j) {
    int col = n0 + wc * 64 + j * 16 + (lane & 15);
    if (col >= ncol) continue;
    float bv = HASBIAS ? bias[col] : 0.f;
#pragma unroll
    for (int i = 0; i < 4; ++i) {
#pragma unroll
      for (int r = 0; r < 4; ++r) {
        int row = m0 + wr * 64 + i * 16 + (lane >> 4) * 4 + r;
        if (row < M) Out[(size_t)row * ldc + col] = acc[i][j][r] + bv;
      }
    }
  }
}

// ================= batch-norm =================
__global__ void k_stats(const float* __restrict__ x, float* __restrict__ stats) {
  int c = threadIdx.x;
  float s = 0.f, ss = 0.f;
  for (int r = blockIdx.x; r < N_NODES; r += gridDim.x) {
    float v = x[(size_t)r * D + c];
    s += v; ss += v * v;
  }
  atomicAdd(&stats[c], s);
  atomicAdd(&stats[D + c], ss);
}

__global__ void k_bnparams(const float* __restrict__ stats, const float* __restrict__ w,
                           const float* __restrict__ b, float* __restrict__ bnp) {
  int set = blockIdx.x, c = threadIdx.x;
  const float* st = stats + (size_t)set * 2 * D;
  float m = st[c] * (1.0f / N_NODES);
  float var = st[D + c] * (1.0f / N_NODES) - m * m;
  float sc = rsqrtf(var + BN_EPS) * w[c];
  bnp[(size_t)set * 2 * D + c] = sc;
  bnp[(size_t)set * 2 * D + D + c] = b[c] - m * sc;
}

// out = relu(h*sc0 + sh0 [+ x2*sc1 + sh1]) -> hi/lo bf16 planes
template <bool ADD2>
__global__ void k_fusebf(const float* __restrict__ h, const float* __restrict__ x2,
                         const float* __restrict__ bnp,
                         unsigned short* __restrict__ hi, unsigned short* __restrict__ lo) {
  int i = blockIdx.x * blockDim.x + threadIdx.x;
  int stride = gridDim.x * blockDim.x;
  const int n4 = N_NODES * D / 4;
  for (; i < n4; i += stride) {
    int row = i >> 6;
    int c4 = (i & 63) * 4;
    float4 hv = ((const float4*)h)[i];
    float4 sc = *(const float4*)&bnp[c4];
    float4 sh = *(const float4*)&bnp[D + c4];
    float4 o;
    o.x = hv.x * sc.x + sh.x; o.y = hv.y * sc.y + sh.y;
    o.z = hv.z * sc.z + sh.z; o.w = hv.w * sc.w + sh.w;
    if (ADD2) {
      float4 pv = ((const float4*)x2)[i];
      float4 sc2 = *(const float4*)&bnp[2 * D + c4];
      float4 sh2 = *(const float4*)&bnp[3 * D + c4];
      o.x += pv.x * sc2.x + sh2.x; o.y += pv.y * sc2.y + sh2.y;
      o.z += pv.z * sc2.z + sh2.z; o.w += pv.w * sc2.w + sh2.w;
    }
    o.x = fmaxf(o.x, 0.f); o.y = fmaxf(o.y, 0.f);
    o.z = fmaxf(o.z, 0.f); o.w = fmaxf(o.w, 0.f);
    ushort4 H, L;
    H.x = f2bf(o.x); L.x = f2bf(o.x - bf2f(H.x));
    H.y = f2bf(o.y); L.y = f2bf(o.y - bf2f(H.y));
    H.z = f2bf(o.z); L.z = f2bf(o.z - bf2f(H.z));
    H.w = f2bf(o.w); L.w = f2bf(o.w - bf2f(H.w));
    *(ushort4*)&hi[(size_t)row * 512 + c4] = H;
    *(ushort4*)&lo[(size_t)row * 256 + c4] = L;
  }
}

extern "C" void kernel_launch(void* const* d_in, const int* in_sizes, int n_in,
                              void* d_out, int out_size, void* d_ws, size_t ws_size,
                              hipStream_t stream) {
  const float* LLM = (const float*)d_in[0];
  const float* PLM = (const float*)d_in[1];
  const int* src = (const int*)d_in[2];
  const int* dst = (const int*)d_in[3];
  const float* ws0 = (const float*)d_in[4];
  const float* wn0 = (const float*)d_in[5];
  const float* b0  = (const float*)d_in[6];
  const float* ws1 = (const float*)d_in[7];
  const float* wn1 = (const float*)d_in[8];
  const float* b1  = (const float*)d_in[9];
  const float* ws2 = (const float*)d_in[10];
  const float* wn2 = (const float*)d_in[11];
  const float* b2  = (const float*)d_in[12];
  const float* bn0w = (const float*)d_in[13];
  const float* bn0b = (const float*)d_in[14];
  const float* bn1w = (const float*)d_in[15];
  const float* bn1b = (const float*)d_in[16];

  float* W = (float*)d_ws;
  // ---- memory map (float offsets), total ~33.4M floats = 133.6 MB ----
  float* f_out = W;                               // [50000][256] f32 (51.2 MB)
  float* f_P   = W + 8000000;                     //   overlay: [50000][80] f32 (layer 2)
  unsigned short* u_hi = (unsigned short*)(W + 12800000);  // [50000][512] bf16 (51.2 MB)
  unsigned short* u_lo = (unsigned short*)(W + 25600000);  // [50000][256] bf16 (25.6 MB)
  int* i_off  = (int*)(W + 32000000);             // NP
  int* i_bsum = i_off + NP;                       // 256
  int* i_cur  = i_bsum + 256;                     // 50048
  int* i_esrc = i_cur + 50048;                    // 800000  (CSR total ~3.6 MB)
  unsigned short* u_w0h = (unsigned short*)(W + 33000000);   // [256][512]
  unsigned short* u_w0l = u_w0h + 131072;
  unsigned short* u_w1h = u_w0l + 131072;
  unsigned short* u_w1l = u_w1h + 131072;
  unsigned short* u_w2h = u_w1l + 131072;         // [80][256]
  unsigned short* u_w2l = u_w2h + 20480;
  float* f_stats = (float*)(u_w2l + 20480);       // 1024
  float* f_bnp   = f_stats + 1024;                // 1024

  // ---- CSR build (once, dedicated region) ----
  hipMemsetAsync(i_off, 0, NP * sizeof(int), stream);
  hipMemsetAsync(f_stats, 0, 1024 * sizeof(float), stream);
  k_hist<<<2048, 256, 0, stream>>>(dst, i_off);
  k_scan1<<<NB, 256, 0, stream>>>(i_off, i_bsum);
  k_scan2<<<1, 256, 0, stream>>>(i_bsum);
  k_scan3<<<NB, 256, 0, stream>>>(i_off, i_bsum);
  k_copycur<<<(N_NODES + 255) / 256, 256, 0, stream>>>(i_off, i_cur);
  k_fill<<<2048, 256, 0, stream>>>(src, dst, i_cur, i_esrc);

  // ---- weight splits ----
  k_wsplit512<<<128, 256, 0, stream>>>(ws0, wn0, u_w0h, u_w0l);
  k_wsplit512<<<128, 256, 0, stream>>>(ws1, wn1, u_w1h, u_w1l);
  k_wsplit2<<<20, 256, 0, stream>>>(ws2, wn2, u_w2h, u_w2l);

  // ---- layer 0 ----
  k_cvt<<<2048, 256, 0, stream>>>(LLM, u_hi, u_lo);
  k_gather_bf<<<12500, 256, 0, stream>>>(u_hi, i_off, i_esrc, u_hi + 256);
  k_bgemm<8, 4, true><<<dim3(391, 2), 256, 0, stream>>>(
      u_hi, 512, u_lo, u_w0h, u_w0l, 512, b0, f_out, N_NODES, 256, 256);
  k_stats<<<512, 256, 0, stream>>>(f_out, f_stats);
  k_stats<<<512, 256, 0, stream>>>(PLM, f_stats + 512);
  k_bnparams<<<2, 256, 0, stream>>>(f_stats, bn0w, bn0b, f_bnp);
  k_fusebf<true><<<2048, 256, 0, stream>>>(f_out, PLM, f_bnp, u_hi, u_lo);

  // ---- layer 1 ----
  hipMemsetAsync(f_stats, 0, 512 * sizeof(float), stream);
  k_gather_bf<<<12500, 256, 0, stream>>>(u_hi, i_off, i_esrc, u_hi + 256);
  k_bgemm<8, 4, true><<<dim3(391, 2), 256, 0, stream>>>(
      u_hi, 512, u_lo, u_w1h, u_w1l, 512, b1, f_out, N_NODES, 256, 256);
  k_stats<<<512, 256, 0, stream>>>(f_out, f_stats);
  k_bnparams<<<1, 256, 0, stream>>>(f_stats, bn1w, bn1b, f_bnp);
  k_fusebf<false><<<2048, 256, 0, stream>>>(f_out, nullptr, f_bnp, u_hi, u_lo);

  // ---- layer 2: project (K=256, h planes only) then gather-mean + epilogue ----
  k_bgemm<4, 4, false><<<dim3(391, 1), 256, 0, stream>>>(
      u_hi, 512, u_lo, u_w2h, u_w2l, 256, nullptr, f_P, N_NODES, 80, 80);
  k_gather40<<<12500, 256, 0, stream>>>(f_P, i_off, i_esrc, b2, (float*)d_out);
}

// Round 12
// 676.965 us; speedup vs baseline: 1.1685x; 1.1685x over previous
//
#include <hip/hip_runtime.h>

#define N_NODES 50000
#define N_EDGES 800000
#define D 256
#define NCLS 40
#define NP 50176   // 196*256 padded histogram/scan size (>= N_NODES+1)
#define NB 196
#define BN_EPS 1e-5f

typedef __attribute__((ext_vector_type(8))) short bf16x8;
typedef __attribute__((ext_vector_type(4))) float f32x4;

__device__ __forceinline__ unsigned short f2bf(float x) {
  unsigned u = __builtin_bit_cast(unsigned, x);
  unsigned r = (u + 0x7FFFu + ((u >> 16) & 1u)) >> 16;
  return (unsigned short)r;
}
__device__ __forceinline__ float bf2f(unsigned short h) {
  unsigned u = ((unsigned)h) << 16;
  return __builtin_bit_cast(float, u);
}

// ================= CSR build =================
__global__ void k_hist(const int* __restrict__ dst, int* __restrict__ cnt) {
  int i = blockIdx.x * blockDim.x + threadIdx.x;
  int stride = gridDim.x * blockDim.x;
  for (; i < N_EDGES; i += stride) atomicAdd(&cnt[dst[i] + 1], 1);
}

__global__ void k_scan1(int* __restrict__ a, int* __restrict__ bsum) {
  __shared__ int s[256];
  int i = blockIdx.x * 256 + threadIdx.x;
  s[threadIdx.x] = a[i];
  __syncthreads();
#pragma unroll
  for (int o = 1; o < 256; o <<= 1) {
    int t = (threadIdx.x >= o) ? s[threadIdx.x - o] : 0;
    __syncthreads();
    s[threadIdx.x] += t;
    __syncthreads();
  }
  a[i] = s[threadIdx.x];
  if (threadIdx.x == 255) bsum[blockIdx.x] = s[255];
}

__global__ void k_scan2(int* __restrict__ bsum) {
  __shared__ int s[256];
  int t = threadIdx.x;
  s[t] = (t < NB) ? bsum[t] : 0;
  __syncthreads();
#pragma unroll
  for (int o = 1; o < 256; o <<= 1) {
    int x = (t >= o) ? s[t - o] : 0;
    __syncthreads();
    s[t] += x;
    __syncthreads();
  }
  if (t < NB) bsum[t] = (t == 0) ? 0 : s[t - 1];
}

__global__ void k_scan3(int* __restrict__ a, const int* __restrict__ bsum) {
  if (blockIdx.x == 0) return;
  int i = blockIdx.x * 256 + threadIdx.x;
  a[i] += bsum[blockIdx.x];
}

__global__ void k_copycur(const int* __restrict__ off, int* __restrict__ cur) {
  int i = blockIdx.x * blockDim.x + threadIdx.x;
  if (i < N_NODES) cur[i] = off[i];
}

__global__ void k_fill(const int* __restrict__ src, const int* __restrict__ dst,
                       int* __restrict__ cur, int* __restrict__ esrc) {
  int i = blockIdx.x * blockDim.x + threadIdx.x;
  int stride = gridDim.x * blockDim.x;
  for (; i < N_EDGES; i += stride) {
    int p = atomicAdd(&cur[dst[i]], 1);
    esrc[p] = src[i];
  }
}

// ====== gather-mean over bf16 table (stride-512 rows), output bf16; unroll-4 ======
__global__ __launch_bounds__(256) void k_gather_bf(const unsigned short* __restrict__ feat,
                                                   const int* __restrict__ off,
                                                   const int* __restrict__ esrc,
                                                   unsigned short* __restrict__ aggout) {
  int wave = blockIdx.x * 4 + (threadIdx.x >> 6);
  int lane = threadIdx.x & 63;
  if (wave >= N_NODES) return;
  int s0 = off[wave], s1 = off[wave + 1];
  float a0 = 0.f, a1 = 0.f, a2 = 0.f, a3 = 0.f;
  int j = s0;
  for (; j + 3 < s1; j += 4) {
    int sa = esrc[j], sb = esrc[j + 1], sc = esrc[j + 2], sd = esrc[j + 3];
    ushort4 va = *(const ushort4*)&feat[(size_t)sa * 512 + lane * 4];
    ushort4 vb = *(const ushort4*)&feat[(size_t)sb * 512 + lane * 4];
    ushort4 vc = *(const ushort4*)&feat[(size_t)sc * 512 + lane * 4];
    ushort4 vd = *(const ushort4*)&feat[(size_t)sd * 512 + lane * 4];
    a0 += (bf2f(va.x) + bf2f(vb.x)) + (bf2f(vc.x) + bf2f(vd.x));
    a1 += (bf2f(va.y) + bf2f(vb.y)) + (bf2f(vc.y) + bf2f(vd.y));
    a2 += (bf2f(va.z) + bf2f(vb.z)) + (bf2f(vc.z) + bf2f(vd.z));
    a3 += (bf2f(va.w) + bf2f(vb.w)) + (bf2f(vc.w) + bf2f(vd.w));
  }
  for (; j < s1; ++j) {
    int sa = esrc[j];
    ushort4 va = *(const ushort4*)&feat[(size_t)sa * 512 + lane * 4];
    a0 += bf2f(va.x); a1 += bf2f(va.y); a2 += bf2f(va.z); a3 += bf2f(va.w);
  }
  float inv = 1.0f / fmaxf((float)(s1 - s0), 1.0f);
  ushort4 o;
  o.x = f2bf(a0 * inv); o.y = f2bf(a1 * inv);
  o.z = f2bf(a2 * inv); o.w = f2bf(a3 * inv);
  *(ushort4*)&aggout[(size_t)wave * 512 + lane * 4] = o;
}

// ====== gather-mean (40 ch, f32 P) fused with final epilogue; unroll-4 ======
__global__ __launch_bounds__(256) void k_gather40(const float* __restrict__ P,
                                                  const int* __restrict__ off,
                                                  const int* __restrict__ esrc,
                                                  const float* __restrict__ b2,
                                                  float* __restrict__ out) {
  int wave = blockIdx.x * 4 + (threadIdx.x >> 6);
  int lane = threadIdx.x & 63;
  if (wave >= N_NODES || lane >= NCLS) return;
  int s0 = off[wave], s1 = off[wave + 1];
  float acc = 0.f;
  int j = s0;
  for (; j + 3 < s1; j += 4) {
    int sa = esrc[j], sb = esrc[j + 1], sc = esrc[j + 2], sd = esrc[j + 3];
    float va = P[(size_t)sa * 80 + NCLS + lane];
    float vb = P[(size_t)sb * 80 + NCLS + lane];
    float vc = P[(size_t)sc * 80 + NCLS + lane];
    float vd = P[(size_t)sd * 80 + NCLS + lane];
    acc += (va + vb) + (vc + vd);
  }
  for (; j < s1; ++j) {
    int s = esrc[j];
    acc += P[(size_t)s * 80 + NCLS + lane];
  }
  float inv = 1.0f / fmaxf((float)(s1 - s0), 1.0f);
  out[(size_t)wave * NCLS + lane] = P[(size_t)wave * 80 + lane] + b2[lane] + acc * inv;
}

// ====== f32 -> hi/lo bf16 planes (layer-0 LLM features) ======
__global__ void k_cvt(const float* __restrict__ x, unsigned short* __restrict__ hi,
                      unsigned short* __restrict__ lo) {
  int i = blockIdx.x * blockDim.x + threadIdx.x;
  int stride = gridDim.x * blockDim.x;
  const int n4 = N_NODES * D / 4;
  for (; i < n4; i += stride) {
    int row = i >> 6;
    int c4 = (i & 63) * 4;
    float4 v = ((const float4*)x)[i];
    ushort4 h, l;
    h.x = f2bf(v.x); l.x = f2bf(v.x - bf2f(h.x));
    h.y = f2bf(v.y); l.y = f2bf(v.y - bf2f(h.y));
    h.z = f2bf(v.z); l.z = f2bf(v.z - bf2f(h.z));
    h.w = f2bf(v.w); l.w = f2bf(v.w - bf2f(h.w));
    *(ushort4*)&hi[(size_t)row * 512 + c4] = h;
    *(ushort4*)&lo[(size_t)row * 256 + c4] = l;
  }
}

// ====== weight split: Wcat [256][512] hi/lo from W1,W2 [256][256] ======
__global__ void k_wsplit512(const float* __restrict__ W1, const float* __restrict__ W2,
                            unsigned short* __restrict__ Wh, unsigned short* __restrict__ Wl) {
  int i = blockIdx.x * blockDim.x + threadIdx.x;
  if (i >= 256 * 128) return;
  int row = i >> 7;
  int c4 = (i & 127) * 4;
  const float* srcp = (c4 < 256) ? &W1[(size_t)row * 256 + c4] : &W2[(size_t)row * 256 + c4 - 256];
  float4 v = *(const float4*)srcp;
  ushort4 h, l;
  h.x = f2bf(v.x); l.x = f2bf(v.x - bf2f(h.x));
  h.y = f2bf(v.y); l.y = f2bf(v.y - bf2f(h.y));
  h.z = f2bf(v.z); l.z = f2bf(v.z - bf2f(h.z));
  h.w = f2bf(v.w); l.w = f2bf(v.w - bf2f(h.w));
  *(ushort4*)&Wh[(size_t)row * 512 + c4] = h;
  *(ushort4*)&Wl[(size_t)row * 512 + c4] = l;
}

// ====== weight split layer 2: Wcat2 [80][256] hi/lo from ws2,wn2 [40][256] ======
__global__ void k_wsplit2(const float* __restrict__ ws2, const float* __restrict__ wn2,
                          unsigned short* __restrict__ Wh, unsigned short* __restrict__ Wl) {
  int i = blockIdx.x * blockDim.x + threadIdx.x;
  if (i >= 80 * 64) return;
  int row = i >> 6;
  int c4 = (i & 63) * 4;
  const float* srcp = (row < NCLS) ? &ws2[(size_t)row * 256 + c4]
                                   : &wn2[(size_t)(row - NCLS) * 256 + c4];
  float4 v = *(const float4*)srcp;
  ushort4 h, l;
  h.x = f2bf(v.x); l.x = f2bf(v.x - bf2f(h.x));
  h.y = f2bf(v.y); l.y = f2bf(v.y - bf2f(h.y));
  h.z = f2bf(v.z); l.z = f2bf(v.z - bf2f(h.z));
  h.w = f2bf(v.w); l.w = f2bf(v.w - bf2f(h.w));
  *(ushort4*)&Wh[(size_t)row * 256 + c4] = h;
  *(ushort4*)&Wl[(size_t)row * 256 + c4] = l;
}

// ========== bf16 MFMA GEMM, LDS-staged A+W with register prefetch ==========
// R8 structure (64 KB LDS, proven) + T14 reorder: step s+1's global->reg loads issue
// between LDS-write and consume-barrier of step s, hiding global latency under MFMAs.
// STATS: fuse per-channel sum/sumsq of output (incl. bias) via shfl butterfly + atomics.
template <int NSTEPS, int NLO, bool HASBIAS, bool STATS>
__global__ __launch_bounds__(256) void k_bgemm(
    const unsigned short* __restrict__ Ah, int strideA,
    const unsigned short* __restrict__ Al,
    const unsigned short* __restrict__ Wh, const unsigned short* __restrict__ Wl, int strideW,
    const float* __restrict__ bias,
    float* __restrict__ Out, int M, int ncol, int ldc, float* __restrict__ stats) {
  __shared__ short sAh[128 * 64], sAl[128 * 64], sWh[128 * 64], sWl[128 * 64];
  const int tid = threadIdx.x;
  const int lane = tid & 63;
  const int wv = tid >> 6;
  const int wr = wv >> 1, wc = wv & 1;
  const int m0 = blockIdx.x * 128, n0 = blockIdx.y * 128;

  f32x4 acc[4][4] = {};

  const int sr = tid >> 1;            // staging row 0..127
  const int sk2 = (tid & 1) * 32;     // bf16 col offset 0/32
  int arow = m0 + sr; if (arow > M - 1) arow = M - 1;
  int wrow = n0 + sr; if (wrow > ncol - 1) wrow = ncol - 1;

  // prologue: load step 0 into registers
  bf16x8 ra[4], ral[4], rw[4], rwl[4];
  {
    const unsigned short* pa  = Ah + (size_t)arow * strideA + sk2;
    const unsigned short* pal = Al + (size_t)arow * 256 + sk2;
    const unsigned short* pw  = Wh + (size_t)wrow * strideW + sk2;
    const unsigned short* pwl = Wl + (size_t)wrow * strideW + sk2;
#pragma unroll
    for (int c = 0; c < 4; ++c) {
      ra[c]  = *(const bf16x8*)(pa + c * 8);
      rw[c]  = *(const bf16x8*)(pw + c * 8);
      rwl[c] = *(const bf16x8*)(pwl + c * 8);
      if (NLO > 0) ral[c] = *(const bf16x8*)(pal + c * 8);
    }
  }

#pragma unroll
  for (int s = 0; s < NSTEPS; ++s) {
    const bool withLo = (s < NLO);
    __syncthreads();  // previous step's LDS reads complete
#pragma unroll
    for (int c = 0; c < 4; ++c) {
      int byte = (sk2 + c * 8) * 2;
      int idx = (sr * 128 + (byte ^ ((sr & 7) << 4))) >> 1;
      *(bf16x8*)&sAh[idx] = ra[c];
      *(bf16x8*)&sWh[idx] = rw[c];
      *(bf16x8*)&sWl[idx] = rwl[c];
      if (withLo) *(bf16x8*)&sAl[idx] = ral[c];
    }
    // prefetch step s+1: loads complete under this step's MFMAs
    if (s + 1 < NSTEPS) {
      const int k1 = (s + 1) * 64;
      const unsigned short* pa  = Ah + (size_t)arow * strideA + k1 + sk2;
      const unsigned short* pal = Al + (size_t)arow * 256 + k1 + sk2;
      const unsigned short* pw  = Wh + (size_t)wrow * strideW + k1 + sk2;
      const unsigned short* pwl = Wl + (size_t)wrow * strideW + k1 + sk2;
#pragma unroll
      for (int c = 0; c < 4; ++c) {
        ra[c]  = *(const bf16x8*)(pa + c * 8);
        rw[c]  = *(const bf16x8*)(pw + c * 8);
        rwl[c] = *(const bf16x8*)(pwl + c * 8);
        if (s + 1 < NLO) ral[c] = *(const bf16x8*)(pal + c * 8);
      }
    }
    __syncthreads();  // LDS writes visible
#pragma unroll
    for (int ks = 0; ks < 2; ++ks) {
      bf16x8 a_h[4], a_l[4], w_h[4], w_l[4];
      const int kb = ks * 64 + (lane >> 4) * 16;
#pragma unroll
      for (int i = 0; i < 4; ++i) {
        int rowA = wr * 64 + i * 16 + (lane & 15);
        int adA = (rowA * 128 + (kb ^ ((rowA & 7) << 4))) >> 1;
        a_h[i] = *(bf16x8*)&sAh[adA];
        if (withLo) a_l[i] = *(bf16x8*)&sAl[adA];
        int rowW = wc * 64 + i * 16 + (lane & 15);
        int adW = (rowW * 128 + (kb ^ ((rowW & 7) << 4))) >> 1;
        w_h[i] = *(bf16x8*)&sWh[adW];
        w_l[i] = *(bf16x8*)&sWl[adW];
      }
#pragma unroll
      for (int i = 0; i < 4; ++i)
#pragma unroll
        for (int j = 0; j < 4; ++j) {
          acc[i][j] = __builtin_amdgcn_mfma_f32_16x16x32_bf16(a_h[i], w_h[j], acc[i][j], 0, 0, 0);
          acc[i][j] = __builtin_amdgcn_mfma_f32_16x16x32_bf16(a_h[i], w_l[j], acc[i][j], 0, 0, 0);
          if (withLo)
            acc[i][j] = __builtin_amdgcn_mfma_f32_16x16x32_bf16(a_l[i], w_h[j], acc[i][j], 0, 0, 0);
        }
    }
  }
  // epilogue: C[row][col]; optional fused per-channel stats (sum, sumsq incl. bias)
#pragma unroll
  for (int j = 0; j < 4; ++j) {
    int col = n0 + wc * 64 + j * 16 + (lane & 15);
    if (col >= ncol) continue;
    float bv = HASBIAS ? bias[col] : 0.f;
    float s = 0.f, ss = 0.f;
#pragma unroll
    for (int i = 0; i < 4; ++i) {
#pragma unroll
      for (int r = 0; r < 4; ++r) {
        int row = m0 + wr * 64 + i * 16 + (lane >> 4) * 4 + r;
        if (row < M) {
          float v = acc[i][j][r] + bv;
          Out[(size_t)row * ldc + col] = v;
          if (STATS) { s += v; ss += v * v; }
        }
      }
    }
    if (STATS) {
      s  += __shfl_xor(s, 16);  s  += __shfl_xor(s, 32);
      ss += __shfl_xor(ss, 16); ss += __shfl_xor(ss, 32);
      if ((lane >> 4) == 0) {
        atomicAdd(&stats[col], s);
        atomicAdd(&stats[D + col], ss);
      }
    }
  }
}

// ================= batch-norm =================
__global__ void k_stats(const float* __restrict__ x, float* __restrict__ stats) {
  int c = threadIdx.x;
  float s = 0.f, ss = 0.f;
  for (int r = blockIdx.x; r < N_NODES; r += gridDim.x) {
    float v = x[(size_t)r * D + c];
    s += v; ss += v * v;
  }
  atomicAdd(&stats[c], s);
  atomicAdd(&stats[D + c], ss);
}

__global__ void k_bnparams(const float* __restrict__ stats, const float* __restrict__ w,
                           const float* __restrict__ b, float* __restrict__ bnp) {
  int set = blockIdx.x, c = threadIdx.x;
  const float* st = stats + (size_t)set * 2 * D;
  float m = st[c] * (1.0f / N_NODES);
  float var = st[D + c] * (1.0f / N_NODES) - m * m;
  float sc = rsqrtf(var + BN_EPS) * w[c];
  bnp[(size_t)set * 2 * D + c] = sc;
  bnp[(size_t)set * 2 * D + D + c] = b[c] - m * sc;
}

// out = relu(h*sc0 + sh0 [+ x2*sc1 + sh1]) -> hi/lo bf16 planes
template <bool ADD2>
__global__ void k_fusebf(const float* __restrict__ h, const float* __restrict__ x2,
                         const float* __restrict__ bnp,
                         unsigned short* __restrict__ hi, unsigned short* __restrict__ lo) {
  int i = blockIdx.x * blockDim.x + threadIdx.x;
  int stride = gridDim.x * blockDim.x;
  const int n4 = N_NODES * D / 4;
  for (; i < n4; i += stride) {
    int row = i >> 6;
    int c4 = (i & 63) * 4;
    float4 hv = ((const float4*)h)[i];
    float4 sc = *(const float4*)&bnp[c4];
    float4 sh = *(const float4*)&bnp[D + c4];
    float4 o;
    o.x = hv.x * sc.x + sh.x; o.y = hv.y * sc.y + sh.y;
    o.z = hv.z * sc.z + sh.z; o.w = hv.w * sc.w + sh.w;
    if (ADD2) {
      float4 pv = ((const float4*)x2)[i];
      float4 sc2 = *(const float4*)&bnp[2 * D + c4];
      float4 sh2 = *(const float4*)&bnp[3 * D + c4];
      o.x += pv.x * sc2.x + sh2.x; o.y += pv.y * sc2.y + sh2.y;
      o.z += pv.z * sc2.z + sh2.z; o.w += pv.w * sc2.w + sh2.w;
    }
    o.x = fmaxf(o.x, 0.f); o.y = fmaxf(o.y, 0.f);
    o.z = fmaxf(o.z, 0.f); o.w = fmaxf(o.w, 0.f);
    ushort4 H, L;
    H.x = f2bf(o.x); L.x = f2bf(o.x - bf2f(H.x));
    H.y = f2bf(o.y); L.y = f2bf(o.y - bf2f(H.y));
    H.z = f2bf(o.z); L.z = f2bf(o.z - bf2f(H.z));
    H.w = f2bf(o.w); L.w = f2bf(o.w - bf2f(H.w));
    *(ushort4*)&hi[(size_t)row * 512 + c4] = H;
    *(ushort4*)&lo[(size_t)row * 256 + c4] = L;
  }
}

extern "C" void kernel_launch(void* const* d_in, const int* in_sizes, int n_in,
                              void* d_out, int out_size, void* d_ws, size_t ws_size,
                              hipStream_t stream) {
  const float* LLM = (const float*)d_in[0];
  const float* PLM = (const float*)d_in[1];
  const int* src = (const int*)d_in[2];
  const int* dst = (const int*)d_in[3];
  const float* ws0 = (const float*)d_in[4];
  const float* wn0 = (const float*)d_in[5];
  const float* b0  = (const float*)d_in[6];
  const float* ws1 = (const float*)d_in[7];
  const float* wn1 = (const float*)d_in[8];
  const float* b1  = (const float*)d_in[9];
  const float* ws2 = (const float*)d_in[10];
  const float* wn2 = (const float*)d_in[11];
  const float* b2  = (const float*)d_in[12];
  const float* bn0w = (const float*)d_in[13];
  const float* bn0b = (const float*)d_in[14];
  const float* bn1w = (const float*)d_in[15];
  const float* bn1b = (const float*)d_in[16];

  float* W = (float*)d_ws;
  // ---- memory map (float offsets), total ~33.4M floats = 133.6 MB ----
  float* f_out = W;                               // [50000][256] f32 (51.2 MB)
  float* f_P   = W + 8000000;                     //   overlay: [50000][80] f32 (layer 2)
  unsigned short* u_hi = (unsigned short*)(W + 12800000);  // [50000][512] bf16 (51.2 MB)
  unsigned short* u_lo = (unsigned short*)(W + 25600000);  // [50000][256] bf16 (25.6 MB)
  int* i_off  = (int*)(W + 32000000);             // NP
  int* i_bsum = i_off + NP;                       // 256
  int* i_cur  = i_bsum + 256;                     // 50048
  int* i_esrc = i_cur + 50048;                    // 800000  (CSR total ~3.6 MB)
  unsigned short* u_w0h = (unsigned short*)(W + 33000000);   // [256][512]
  unsigned short* u_w0l = u_w0h + 131072;
  unsigned short* u_w1h = u_w0l + 131072;
  unsigned short* u_w1l = u_w1h + 131072;
  unsigned short* u_w2h = u_w1l + 131072;         // [80][256]
  unsigned short* u_w2l = u_w2h + 20480;
  float* f_stats = (float*)(u_w2l + 20480);       // 1024
  float* f_bnp   = f_stats + 1024;                // 1024

  // ---- CSR build (once, dedicated region) ----
  hipMemsetAsync(i_off, 0, NP * sizeof(int), stream);
  hipMemsetAsync(f_stats, 0, 1024 * sizeof(float), stream);
  k_hist<<<2048, 256, 0, stream>>>(dst, i_off);
  k_scan1<<<NB, 256, 0, stream>>>(i_off, i_bsum);
  k_scan2<<<1, 256, 0, stream>>>(i_bsum);
  k_scan3<<<NB, 256, 0, stream>>>(i_off, i_bsum);
  k_copycur<<<(N_NODES + 255) / 256, 256, 0, stream>>>(i_off, i_cur);
  k_fill<<<2048, 256, 0, stream>>>(src, dst, i_cur, i_esrc);

  // ---- weight splits ----
  k_wsplit512<<<128, 256, 0, stream>>>(ws0, wn0, u_w0h, u_w0l);
  k_wsplit512<<<128, 256, 0, stream>>>(ws1, wn1, u_w1h, u_w1l);
  k_wsplit2<<<20, 256, 0, stream>>>(ws2, wn2, u_w2h, u_w2l);

  // ---- layer 0 ----
  k_cvt<<<2048, 256, 0, stream>>>(LLM, u_hi, u_lo);
  k_gather_bf<<<12500, 256, 0, stream>>>(u_hi, i_off, i_esrc, u_hi + 256);
  k_bgemm<8, 4, true, true><<<dim3(391, 2), 256, 0, stream>>>(
      u_hi, 512, u_lo, u_w0h, u_w0l, 512, b0, f_out, N_NODES, 256, 256, f_stats);
  k_stats<<<512, 256, 0, stream>>>(PLM, f_stats + 512);
  k_bnparams<<<2, 256, 0, stream>>>(f_stats, bn0w, bn0b, f_bnp);
  k_fusebf<true><<<2048, 256, 0, stream>>>(f_out, PLM, f_bnp, u_hi, u_lo);

  // ---- layer 1 ----
  hipMemsetAsync(f_stats, 0, 512 * sizeof(float), stream);
  k_gather_bf<<<12500, 256, 0, stream>>>(u_hi, i_off, i_esrc, u_hi + 256);
  k_bgemm<8, 4, true, true><<<dim3(391, 2), 256, 0, stream>>>(
      u_hi, 512, u_lo, u_w1h, u_w1l, 512, b1, f_out, N_NODES, 256, 256, f_stats);
  k_bnparams<<<1, 256, 0, stream>>>(f_stats, bn1w, bn1b, f_bnp);
  k_fusebf<false><<<2048, 256, 0, stream>>>(f_out, nullptr, f_bnp, u_hi, u_lo);

  // ---- layer 2: project (K=256, hi/lo planes) then gather-mean + epilogue ----
  k_bgemm<4, 4, false, false><<<dim3(391, 1), 256, 0, stream>>>(
      u_hi, 512, u_lo, u_w2h, u_w2l, 256, nullptr, f_P, N_NODES, 80, 80, nullptr);
  k_gather40<<<12500, 256, 0, stream>>>(f_P, i_off, i_esrc, b2, (float*)d_out);
}